// Round 11
// baseline (1432.881 us; speedup 1.0000x reference)
//
#include <hip/hip_runtime.h>
#include <hip/hip_bf16.h>

#define N_NODES 100000
#define N_EDGES 1600000
#define N_STEPS 10

// ---- RK45 (Dormand-Prince) coefficients, fp32 ----
#define Hc   0.1f
#define A21c 0.2f
#define A31c (float)(3.0/40.0)
#define A32c (float)(9.0/40.0)
#define A41c (float)(44.0/45.0)
#define A42c (float)(-56.0/15.0)
#define A43c (float)(32.0/9.0)
#define A51c (float)(19372.0/6561.0)
#define A52c (float)(-25360.0/2187.0)
#define A53c (float)(64448.0/6561.0)
#define A54c (float)(-212.0/729.0)
#define A61c (float)(9017.0/3168.0)
#define A62c (float)(-355.0/33.0)
#define A63c (float)(46732.0/5247.0)
#define A64c (float)(49.0/176.0)
#define A65c (float)(-5103.0/18656.0)
#define B1c  (float)(35.0/384.0)
#define B3c  (float)(500.0/1113.0)
#define B4c  (float)(125.0/192.0)
#define B5c  (float)(-2187.0/6784.0)
#define B6c  (float)(11.0/84.0)

// Zero workspace region (re-poisoned 0xAA each call).
__global__ void zero_ws_kernel(float4* ws, int n4) {
    int i = blockIdx.x * blockDim.x + threadIdx.x;
    if (i < n4) ws[i] = make_float4(0.f, 0.f, 0.f, 0.f);
}

// ============ CSR path (3.2M int atomics instead of 32M float) ============

__global__ __launch_bounds__(256) void encode_count_kernel(
    const float* __restrict__ edges,
    const int* __restrict__ senders,
    const int* __restrict__ receivers,
    const float* __restrict__ W,    // (3,10)
    const float* __restrict__ b,    // (10)
    const float* __restrict__ Wd,   // (10,1)
    const float* __restrict__ bd,   // (1)
    int* __restrict__ cnt,          // (2*N_NODES) counters, zeroed
    int* __restrict__ pos_s,        // (N_EDGES)
    int* __restrict__ pos_r,        // (N_EDGES)
    float* __restrict__ dec_e)      // (N_EDGES)
{
    int e = blockIdx.x * 256 + threadIdx.x;
    if (e >= N_EDGES) return;
    float e0 = edges[e*3+0], e1 = edges[e*3+1], e2 = edges[e*3+2];
    float d = bd[0];
    #pragma unroll
    for (int j = 0; j < 10; ++j) {
        float he = fmaf(e0, W[j], fmaf(e1, W[10+j], fmaf(e2, W[20+j], b[j])));
        d = fmaf(he, Wd[j], d);
    }
    dec_e[e] = d;
    int s = senders[e], r = receivers[e];
    pos_s[e] = atomicAdd(&cnt[s], 1);
    pos_r[e] = atomicAdd(&cnt[N_NODES + r], 1);
}

// Single-block exclusive scan of n ints in-place (n = 200000).
__global__ __launch_bounds__(1024) void scan_kernel(int* __restrict__ data, int n) {
    __shared__ int lds[1024];
    const int t = threadIdx.x;
    const int CH = (n + 1023) / 1024;
    int lo = t * CH;
    int hi = lo + CH; if (hi > n) hi = n;
    int sum = 0;
    for (int i = lo; i < hi; ++i) sum += data[i];
    lds[t] = sum;
    __syncthreads();
    for (int off = 1; off < 1024; off <<= 1) {
        int v = (t >= off) ? lds[t - off] : 0;
        __syncthreads();
        lds[t] += v;
        __syncthreads();
    }
    int run = (t == 0) ? 0 : lds[t - 1];
    for (int i = lo; i < hi; ++i) {
        int v = data[i];
        data[i] = run;
        run += v;
    }
}

// Scatter edge ids into CSR slot arrays. No atomics.
__global__ __launch_bounds__(256) void scatter_kernel(
    const int* __restrict__ senders,
    const int* __restrict__ receivers,
    const int* __restrict__ base,   // (2*N_NODES) exclusive prefixes
    const int* __restrict__ pos_s,
    const int* __restrict__ pos_r,
    int* __restrict__ eid)          // (2*N_EDGES)
{
    int e = blockIdx.x * 256 + threadIdx.x;
    if (e >= N_EDGES) return;
    int s = senders[e];
    eid[base[s] + pos_s[e]] = e;
    int r = receivers[e];
    eid[base[N_NODES + r] + pos_r[e]] = e;
}

// Per node+side: walk edge list, recompute h_e, sum, write comp-major.
__global__ __launch_bounds__(256) void gather_kernel(
    const float* __restrict__ edges,
    const float* __restrict__ W,    // (3,10)
    const float* __restrict__ b,    // (10)
    const int* __restrict__ base,   // (2*N_NODES)
    const int* __restrict__ eid,    // (2*N_EDGES)
    float* __restrict__ sent,       // (10, N_NODES)
    float* __restrict__ recv)       // (10, N_NODES)
{
    int n = blockIdx.x * 256 + threadIdx.x;
    if (n >= N_NODES) return;
    int side = blockIdx.y;
    int idx = side * N_NODES + n;
    int start = base[idx];
    int end = (idx + 1 < 2*N_NODES) ? base[idx + 1] : 2*N_EDGES;
    float acc[10];
    #pragma unroll
    for (int j = 0; j < 10; ++j) acc[j] = 0.0f;
    for (int p = start; p < end; ++p) {
        int e = eid[p];
        float e0 = edges[e*3+0], e1 = edges[e*3+1], e2 = edges[e*3+2];
        #pragma unroll
        for (int j = 0; j < 10; ++j)
            acc[j] += fmaf(e0, W[j], fmaf(e1, W[10+j], fmaf(e2, W[20+j], b[j])));
    }
    float* dst = side ? recv : sent;
    #pragma unroll
    for (int j = 0; j < 10; ++j) dst[j*N_NODES + n] = acc[j];
}

// ============ Fallback: measured round-9 atomic path ============

__global__ __launch_bounds__(256) void edge_kernel(
    const float* __restrict__ edges,
    const int* __restrict__ senders,
    const int* __restrict__ receivers,
    const float* __restrict__ W,
    const float* __restrict__ b,
    const float* __restrict__ Wd,
    const float* __restrict__ bd,
    float* __restrict__ sent,       // (10, N_NODES)
    float* __restrict__ recv,       // (10, N_NODES)
    float* __restrict__ dec_e)
{
    int e = blockIdx.x * 256 + threadIdx.x;
    if (e >= N_EDGES) return;
    int side = blockIdx.y;
    float e0 = edges[e*3+0], e1 = edges[e*3+1], e2 = edges[e*3+2];
    float he[10];
    #pragma unroll
    for (int j = 0; j < 10; ++j)
        he[j] = fmaf(e0, W[j], fmaf(e1, W[10+j], fmaf(e2, W[20+j], b[j])));
    if (side == 0) {
        float d = bd[0];
        #pragma unroll
        for (int j = 0; j < 10; ++j) d = fmaf(he[j], Wd[j], d);
        dec_e[e] = d;
        int s = senders[e];
        #pragma unroll
        for (int j = 0; j < 10; ++j) atomicAdd(&sent[j*N_NODES + s], he[j]);
    } else {
        int r = receivers[e];
        #pragma unroll
        for (int j = 0; j < 10; ++j) atomicAdd(&recv[j*N_NODES + r], he[j]);
    }
}

// ============ Node ODE phase ============
// deriv8 round-11 change: BATCH the 32 activation reads into an explicit
// v[32] register array (static indices only) so the 32 ds_read_b32 issue
// back-to-back (pipelined, one lgkmcnt wait) instead of the round-10
// serial read->8xFMA dependency chain (~100cyc exposed per read).
__device__ __forceinline__ void deriv8(
    float (* __restrict__ bufU)[64], float (* __restrict__ bufT)[64],
    int lane, int c0,
    const float* __restrict__ w1s,
    const float* __restrict__ w2s,
    const float* __restrict__ bb1,
    const float* __restrict__ bb2,
    const float* __restrict__ u, float* __restrict__ k)
{
    #pragma unroll
    for (int j = 0; j < 8; ++j) bufU[c0 + j][lane] = u[j];
    __syncthreads();
    float v[32];
    #pragma unroll
    for (int i = 0; i < 32; ++i) v[i] = bufU[i][lane];
    float t[8];
    #pragma unroll
    for (int j = 0; j < 8; ++j) t[j] = bb1[j];
    #pragma unroll
    for (int i = 0; i < 32; ++i) {
        #pragma unroll
        for (int j = 0; j < 8; ++j) t[j] = fmaf(v[i], w1s[i*32 + j], t[j]);
    }
    #pragma unroll
    for (int j = 0; j < 8; ++j) t[j] = fmaxf(t[j], 0.0f);
    #pragma unroll
    for (int j = 0; j < 8; ++j) bufT[c0 + j][lane] = t[j];
    __syncthreads();
    #pragma unroll
    for (int i = 0; i < 32; ++i) v[i] = bufT[i][lane];
    #pragma unroll
    for (int j = 0; j < 8; ++j) k[j] = bb2[j];
    #pragma unroll
    for (int i = 0; i < 32; ++i) {
        #pragma unroll
        for (int j = 0; j < 8; ++j) k[j] = fmaf(v[i], w2s[i*32 + j], k[j]);
    }
}

__global__ __launch_bounds__(256) void node_kernel(
    const float* __restrict__ nodes,
    const float* __restrict__ globals_,
    const float* __restrict__ encW,
    const float* __restrict__ encb,
    const float* __restrict__ W1,
    const float* __restrict__ b1,
    const float* __restrict__ W2,
    const float* __restrict__ b2,
    const float* __restrict__ Wno,
    const float* __restrict__ bno,
    const float* __restrict__ Wdn,
    const float* __restrict__ bdn,
    const float* __restrict__ sent,      // (10, N_NODES) comp-major
    const float* __restrict__ recv,      // (10, N_NODES) comp-major
    float* __restrict__ out_decn,
    float* __restrict__ out_pos,
    float* __restrict__ out_vel)
{
    __shared__ float xb[2][32][64];

    const int tid  = threadIdx.x;
    const int lane = tid & 63;
    const int wq   = __builtin_amdgcn_readfirstlane(tid >> 6);
    const int c0   = wq * 8;
    const int n_raw = blockIdx.x * 64 + lane;
    const int n     = (n_raw < N_NODES) ? n_raw : (N_NODES - 1);

    const float* __restrict__ w1s = W1 + c0;
    const float* __restrict__ w2s = W2 + c0;
    float bb1[8], bb2[8];
    #pragma unroll
    for (int j = 0; j < 8; ++j) { bb1[j] = b1[c0+j]; bb2[j] = b2[c0+j]; }

    const float pos = nodes[n*2+0];
    const float vel = nodes[n*2+1];
    const float g0 = globals_[0], g1 = globals_[1];

    float y[8];
    #pragma unroll
    for (int j = 0; j < 8; ++j) {
        int c = c0 + j;
        float v;
        if (c < 10)      v = fmaf(pos, encW[c], fmaf(vel, encW[10+c], encb[c]));
        else if (c < 20) v = sent[(c-10)*N_NODES + n];
        else if (c < 30) v = recv[(c-20)*N_NODES + n];
        else             v = (c == 30) ? g0 : g1;
        y[j] = v;
    }

    for (int s = 0; s < N_STEPS; ++s) {
        float k1[8], k2[8], k3[8], k4[8], k5[8], kt[8], u[8];
        deriv8(xb[0], xb[1], lane, c0, w1s, w2s, bb1, bb2, y, k1);
        #pragma unroll
        for (int j = 0; j < 8; ++j) u[j] = fmaf(Hc * A21c, k1[j], y[j]);
        deriv8(xb[0], xb[1], lane, c0, w1s, w2s, bb1, bb2, u, k2);
        #pragma unroll
        for (int j = 0; j < 8; ++j)
            u[j] = fmaf(Hc, fmaf(A31c, k1[j], A32c * k2[j]), y[j]);
        deriv8(xb[0], xb[1], lane, c0, w1s, w2s, bb1, bb2, u, k3);
        #pragma unroll
        for (int j = 0; j < 8; ++j)
            u[j] = fmaf(Hc, fmaf(A41c, k1[j], fmaf(A42c, k2[j], A43c * k3[j])), y[j]);
        deriv8(xb[0], xb[1], lane, c0, w1s, w2s, bb1, bb2, u, k4);
        #pragma unroll
        for (int j = 0; j < 8; ++j)
            u[j] = fmaf(Hc, fmaf(A51c, k1[j], fmaf(A52c, k2[j],
                     fmaf(A53c, k3[j], A54c * k4[j]))), y[j]);
        deriv8(xb[0], xb[1], lane, c0, w1s, w2s, bb1, bb2, u, k5);
        #pragma unroll
        for (int j = 0; j < 8; ++j)
            u[j] = fmaf(Hc, fmaf(A61c, k1[j], fmaf(A62c, k2[j],
                     fmaf(A63c, k3[j], fmaf(A64c, k4[j], A65c * k5[j])))), y[j]);
        deriv8(xb[0], xb[1], lane, c0, w1s, w2s, bb1, bb2, u, kt);
        #pragma unroll
        for (int j = 0; j < 8; ++j)
            y[j] = fmaf(Hc, fmaf(B1c, k1[j], fmaf(B3c, k3[j],
                     fmaf(B4c, k4[j], fmaf(B5c, k5[j], B6c * kt[j])))), y[j]);
    }

    float p[10];
    #pragma unroll
    for (int jo = 0; jo < 10; ++jo) p[jo] = 0.0f;
    #pragma unroll
    for (int j = 0; j < 8; ++j) {
        float v = y[j];
        #pragma unroll
        for (int jo = 0; jo < 10; ++jo)
            p[jo] = fmaf(v, Wno[(c0+j)*10 + jo], p[jo]);
    }
    __syncthreads();
    float* pb = &xb[0][0][0];
    #pragma unroll
    for (int jo = 0; jo < 10; ++jo) pb[(wq*10 + jo)*64 + lane] = p[jo];
    __syncthreads();
    if (wq == 0 && n_raw < N_NODES) {
        float dn = bdn[0];
        #pragma unroll
        for (int jo = 0; jo < 10; ++jo) {
            float h2 = bno[jo] + pb[jo*64 + lane] + pb[(10+jo)*64 + lane]
                     + pb[(20+jo)*64 + lane] + pb[(30+jo)*64 + lane];
            dn = fmaf(h2, Wdn[jo], dn);
        }
        out_decn[n] = dn;
        float nv = vel + dn;   // DT = 1
        float np = pos + nv;
        out_pos[n] = np;
        out_vel[n] = nv;
    }
}

extern "C" void kernel_launch(void* const* d_in, const int* in_sizes, int n_in,
                              void* d_out, int out_size, void* d_ws, size_t ws_size,
                              hipStream_t stream) {
    const float* nodes      = (const float*)d_in[0];
    const float* edges      = (const float*)d_in[1];
    const int*   senders    = (const int*)d_in[2];
    const int*   receivers  = (const int*)d_in[3];
    const float* globals_   = (const float*)d_in[4];
    const float* enc_node_W = (const float*)d_in[5];
    const float* enc_node_b = (const float*)d_in[6];
    const float* enc_edge_W = (const float*)d_in[7];
    const float* enc_edge_b = (const float*)d_in[8];
    const float* ode_W1     = (const float*)d_in[9];
    const float* ode_b1     = (const float*)d_in[10];
    const float* ode_W2     = (const float*)d_in[11];
    const float* ode_b2     = (const float*)d_in[12];
    const float* node_out_W = (const float*)d_in[13];
    const float* node_out_b = (const float*)d_in[14];
    const float* dec_node_W = (const float*)d_in[15];
    const float* dec_node_b = (const float*)d_in[16];
    const float* dec_edge_W = (const float*)d_in[17];
    const float* dec_edge_b = (const float*)d_in[18];

    float* out = (float*)d_out;
    float* out_decn = out;                       // [0, 1e5)
    float* out_dece = out + N_NODES;             // [1e5, 1.7e6)
    float* out_pos  = out + N_NODES + N_EDGES;   // [1.7e6, 1.8e6)
    float* out_vel  = out + 2*N_NODES + N_EDGES; // [1.8e6, 1.9e6)

    // Workspace layout
    float* sent = (float*)d_ws;                    // 10*N floats
    float* recv = sent + 10*N_NODES;               // 10*N floats
    int*   base = (int*)(recv + 10*N_NODES);       // 2*N ints (counts -> bases)
    int*   pos_s = base + 2*N_NODES;               // N_EDGES ints
    int*   pos_r = pos_s + N_EDGES;                // N_EDGES ints
    int*   eid   = pos_r + N_EDGES;                // 2*N_EDGES ints

    size_t need = (size_t)(20*N_NODES)*4 + (size_t)(2*N_NODES)*4
                + (size_t)(4*N_EDGES)*4;           // = 34.4 MB

    if (ws_size >= need) {
        // ---- CSR path ----
        zero_ws_kernel<<<(50000 + 255) / 256, 256, 0, stream>>>(
            (float4*)base, 50000);
        encode_count_kernel<<<(N_EDGES + 255) / 256, 256, 0, stream>>>(
            edges, senders, receivers, enc_edge_W, enc_edge_b,
            dec_edge_W, dec_edge_b, base, pos_s, pos_r, out_dece);
        scan_kernel<<<1, 1024, 0, stream>>>(base, 2*N_NODES);
        scatter_kernel<<<(N_EDGES + 255) / 256, 256, 0, stream>>>(
            senders, receivers, base, pos_s, pos_r, eid);
        {
            dim3 grid((N_NODES + 255) / 256, 2);
            gather_kernel<<<grid, 256, 0, stream>>>(
                edges, enc_edge_W, enc_edge_b, base, eid, sent, recv);
        }
    } else {
        // ---- fallback: round-9 atomic path ----
        int n4 = (N_NODES * 10 * 2) / 4;
        zero_ws_kernel<<<(n4 + 255) / 256, 256, 0, stream>>>((float4*)d_ws, n4);
        dim3 grid((N_EDGES + 255) / 256, 2);
        edge_kernel<<<grid, 256, 0, stream>>>(
            edges, senders, receivers, enc_edge_W, enc_edge_b,
            dec_edge_W, dec_edge_b, sent, recv, out_dece);
    }

    // node ODE phase
    node_kernel<<<(N_NODES + 63) / 64, 256, 0, stream>>>(
        nodes, globals_, enc_node_W, enc_node_b,
        ode_W1, ode_b1, ode_W2, ode_b2,
        node_out_W, node_out_b, dec_node_W, dec_node_b,
        sent, recv, out_decn, out_pos, out_vel);
}